// Round 21
// baseline (237.921 us; speedup 1.0000x reference)
//
#include <hip/hip_runtime.h>
#include <hip/hip_bf16.h>

#define D 256
#define BM 64
#define CAPG 92
#define MARGIN 2.5e-4f

typedef short bf16x8 __attribute__((ext_vector_type(8)));
typedef float f32x4 __attribute__((ext_vector_type(4)));

__device__ inline unsigned short f2bf(float f) {
    __hip_bfloat16 h = __float2bfloat16(f);
    return *reinterpret_cast<unsigned short*>(&h);
}
// order-preserving float -> uint (works for negatives; lower float = lower uint)
__device__ inline unsigned f2ord(float f) {
    unsigned u = __float_as_uint(f);
    return (u & 0x80000000u) ? ~u : (u | 0x80000000u);
}
__device__ inline float ord2f(unsigned u) {
    unsigned b = (u & 0x80000000u) ? (u ^ 0x80000000u) : ~u;
    return __uint_as_float(b);
}

// -------- kernel 0: fp32 emb -> bf16 in MFMA-fragment order (R9-verified) ----
__global__ __launch_bounds__(512) void vq_ebfrag(const float* __restrict__ emb,
                                                 unsigned short* __restrict__ ebf) {
    const int cb = blockIdx.x;          // 0..127
    const int tid = threadIdx.x;
    const int kc = tid >> 6;            // wave index == kc 0..7
    const int l = tid & 63;
    const int q = l >> 4, lm = l & 15;
    const float4* emb4 = (const float4*)emb;
    #pragma unroll
    for (int fc = 0; fc < 4; ++fc) {
        const int code = cb * 64 + fc * 16 + lm;
        float4 a = emb4[(size_t)code * 64 + kc * 8 + q * 2];
        float4 b = emb4[(size_t)code * 64 + kc * 8 + q * 2 + 1];
        ushort4 o0, o1;
        o0.x = f2bf(a.x); o0.y = f2bf(a.y); o0.z = f2bf(a.z); o0.w = f2bf(a.w);
        o1.x = f2bf(b.x); o1.y = f2bf(b.y); o1.z = f2bf(b.z); o1.w = f2bf(b.w);
        unsigned short* dst = ebf + (((size_t)(cb * 8 + kc) * 4 + fc) << 9) + l * 8;
        *(ushort4*)dst = o0;
        *(ushort4*)(dst + 4) = o1;
    }
}

// -------- kernel 1: sequential fp32 row sum-of-squares (float4, same chain) ----
__global__ __launch_bounds__(256) void vq_rownorm(const float* __restrict__ x,
                                                  float* __restrict__ out, int rows,
                                                  float* loss_zero, int* cntG) {
#pragma clang fp contract(off)
    int r = blockIdx.x * blockDim.x + threadIdx.x;
    if (r == 0 && loss_zero) loss_zero[0] = 0.f;
    if (r >= rows) return;
    if (cntG) cntG[r] = 0;
    const float4* p4 = (const float4*)(x + (size_t)r * D);
    float s = 0.f;
    for (int i = 0; i < 64; ++i) {       // strict sequential mul+add, ascending d
        float4 v = p4[i];
        s = s + v.x * v.x;
        s = s + v.y * v.y;
        s = s + v.z * v.z;
        s = s + v.w * v.w;
    }
    out[r] = s;
}

// -------- kernel 2: BM=64 quarter-split single-pass MFMA filter ---------------
// block b: rows [(b&255)*64, +64), code quarter b>>8 (2048 codes, 4 tiles of 512)
// NO occupancy hint: let the allocator use ~128 VGPR and auto-pipeline (R9 mode)
__global__ __launch_bounds__(512) void vq_filter(
    const float* __restrict__ z, const unsigned short* __restrict__ ebf,
    const float* __restrict__ enorm,
    int* __restrict__ cntG, int* __restrict__ candC, float* __restrict__ candS) {
#pragma clang fp contract(off)
    __shared__ unsigned short zsh[BM][264];   // 33,792 B
    __shared__ unsigned rowmin[BM];           // ORDERED-uint running min

    const int tid = threadIdx.x;
    const int w = tid >> 6;        // wave 0..7 (64-code column)
    const int l = tid & 63;
    const int q = l >> 4;          // 0..3
    const int lm = l & 15;
    const int b = blockIdx.x;
    const int rowBase = (b & 255) * BM;
    const int qt = b >> 8;         // code quarter 0..3

    if (tid < BM) rowmin[tid] = 0xffffffffu;   // ordered +inf

    // stage z tile: load f32, convert to bf16 inline (64 rows)
    #pragma unroll
    for (int rc = 0; rc < 8; ++rc) {
        int i4 = tid + rc * 512;                  // 4096 float4s
        int row = i4 >> 6, c4 = i4 & 63;
        float4 v = ((const float4*)(z + ((size_t)(rowBase + row) << 8)))[c4];
        ushort4 o;
        o.x = f2bf(v.x); o.y = f2bf(v.y); o.z = f2bf(v.z); o.w = f2bf(v.w);
        *(ushort4*)&zsh[row][c4 * 4] = o;
    }
    __syncthreads();

    for (int t = 0; t < 4; ++t) {
        const int cb = qt * 32 + t * 8 + w;          // wave's 64-code block
        const int codeBase = cb * 64;
        const unsigned short* fb = ebf + ((size_t)cb << 14);
        float ne[4];
        #pragma unroll
        for (int fc = 0; fc < 4; ++fc) ne[fc] = enorm[codeBase + fc * 16 + lm];

        f32x4 acc[4][4];
        #pragma unroll
        for (int a = 0; a < 4; ++a)
            #pragma unroll
            for (int c = 0; c < 4; ++c) acc[a][c] = (f32x4)0.f;

        #pragma unroll
        for (int kc = 0; kc < 8; ++kc) {
            bf16x8 af[4], bfr[4];
            #pragma unroll
            for (int fr = 0; fr < 4; ++fr)
                af[fr] = *(const bf16x8*)&zsh[fr * 16 + lm][kc * 32 + q * 8];
            #pragma unroll
            for (int fc = 0; fc < 4; ++fc)   // contiguous 1 KB per wave-load
                bfr[fc] = *(const bf16x8*)(fb + kc * 2048 + fc * 512 + l * 8);
            #pragma unroll
            for (int fr = 0; fr < 4; ++fr)
                #pragma unroll
                for (int fc = 0; fc < 4; ++fc)
                    acc[fr][fc] = __builtin_amdgcn_mfma_f32_16x16x32_bf16(af[fr], bfr[fc], acc[fr][fc], 0, 0, 0);
        }

        // ---- epilogue: s' = ne - 2g (may be NEGATIVE -> ordered atomics) ----
        f32x4 m4[4];
        #pragma unroll
        for (int fr = 0; fr < 4; ++fr) {
            #pragma unroll
            for (int e = 0; e < 4; ++e) {
                float m = 3.4e38f;
                #pragma unroll
                for (int fc = 0; fc < 4; ++fc) {
                    float s = ne[fc] - 2.0f * acc[fr][fc][e];
                    m = fminf(m, s);
                }
                m4[fr][e] = m;
                #pragma unroll
                for (int off = 1; off < 16; off <<= 1)
                    m = fminf(m, __shfl_xor(m, off));
                if (lm == 0)
                    atomicMin(&rowmin[fr * 16 + q * 4 + e], f2ord(m));
            }
        }
        // collect vs running threshold (ordered decode)
        #pragma unroll
        for (int fr = 0; fr < 4; ++fr) {
            uint4 u = *(const uint4*)&rowmin[fr * 16 + q * 4];
            f32x4 thr = {ord2f(u.x) + MARGIN, ord2f(u.y) + MARGIN,
                         ord2f(u.z) + MARGIN, ord2f(u.w) + MARGIN};
            #pragma unroll
            for (int e = 0; e < 4; ++e) {
                if (m4[fr][e] >= thr[e]) continue;   // fast skip
                int row = rowBase + fr * 16 + q * 4 + e;
                #pragma unroll
                for (int fc = 0; fc < 4; ++fc) {
                    float s = ne[fc] - 2.0f * acc[fr][fc][e];
                    if (s < thr[e]) {
                        int slot = atomicAdd(&cntG[row], 1);
                        if (slot < CAPG) {
                            candC[(size_t)row * CAPG + slot] = codeBase + fc * 16 + lm;
                            candS[(size_t)row * CAPG + slot] = s;
                        }
                    }
                }
            }
        }
    }
}

// -------- kernel 3: pruned exact rescore (bit-exact R2 semantics) --------
__global__ __launch_bounds__(256) void vq_rescore(
    const float* __restrict__ z, const float* __restrict__ emb,
    const float* __restrict__ znorm, const float* __restrict__ enorm,
    const int* __restrict__ cntG, const int* __restrict__ candC,
    const float* __restrict__ candS, float* __restrict__ idxf, int K) {
#pragma clang fp contract(off)
    __shared__ unsigned sapx[64];   // ordered min approx score
    __shared__ unsigned sbits[64];  // exact score bits (always >= 0)
    __shared__ int sidx[64];
    __shared__ int ovList[64];
    __shared__ int ovCnt;

    const int tid = threadIdx.x;
    const int rowBase = blockIdx.x * 64;
    if (tid < 64) { sapx[tid] = 0xffffffffu; sbits[tid] = 0xffffffffu; sidx[tid] = 0x7fffffff; }
    if (tid == 0) ovCnt = 0;
    __syncthreads();

    const int r = tid & 63;        // one row per lane
    const int c0 = tid >> 6;       // 4 workers per row
    const int grow = rowBase + r;
    const int n = min(cntG[grow], CAPG);

    // phase 1: min approx score over stored candidates (ordered atomics)
    {
        float amin = 3.4e38f;
        for (int c = c0; c < n; c += 4)
            amin = fminf(amin, candS[(size_t)grow * CAPG + c]);
        atomicMin(&sapx[r], f2ord(amin));
    }
    if (tid < 64 && cntG[rowBase + tid] > CAPG) {      // overflow rows -> exact scan
        int o = atomicAdd(&ovCnt, 1);
        ovList[o] = tid;                               // total safety
    }
    __syncthreads();

    // phase 2: exact rescore only candidates within MARGIN of min approx
    const float Anz = znorm[grow];
    const float4* zp4 = (const float4*)(z + ((size_t)grow << 8));
    const float athr = ord2f(sapx[r]) + MARGIN;

    float bestS = 3.4e38f; int bestK = 0x7fffffff;
    for (int c = c0; c < n; c += 4) {
        if (candS[(size_t)grow * CAPG + c] > athr) continue;   // pruned: 8B not 1KB
        int k = candC[(size_t)grow * CAPG + c];
        const float4* ep4 = (const float4*)(emb + ((size_t)k << 8));
        float s = 0.f;
        #pragma unroll 8
        for (int d4 = 0; d4 < 64; ++d4) {
            float4 a = zp4[d4], b = ep4[d4];
            s = s + a.x * b.x;   // strict mul-then-add, ascending d
            s = s + a.y * b.y;
            s = s + a.z * b.z;
            s = s + a.w * b.w;
        }
        float sc = (Anz + enorm[k]) - 2.0f * s;
        if (sc < bestS || (sc == bestS && k < bestK)) { bestS = sc; bestK = k; }
    }
    if (bestK != 0x7fffffff) atomicMin(&sbits[r], __float_as_uint(bestS));
    __syncthreads();

    // cooperative fallback: full exact scan for every overflow row
    const int nov = ovCnt;
    for (int o = 0; o < nov; ++o) {
        const int rr = ovList[o];
        const float Az = znorm[rowBase + rr];
        const float4* zr4 = (const float4*)(z + ((size_t)(rowBase + rr) << 8));
        float bS = 3.4e38f; int bK = 0x7fffffff;
        for (int k = tid; k < K; k += 256) {
            const float4* ep4 = (const float4*)(emb + ((size_t)k << 8));
            float s = 0.f;
            #pragma unroll 8
            for (int d4 = 0; d4 < 64; ++d4) {
                float4 a = zr4[d4], b = ep4[d4];
                s = s + a.x * b.x; s = s + a.y * b.y;
                s = s + a.z * b.z; s = s + a.w * b.w;
            }
            float sc = (Az + enorm[k]) - 2.0f * s;
            if (sc < bS || (sc == bS && k < bK)) { bS = sc; bK = k; }
        }
        atomicMin(&sbits[rr], __float_as_uint(bS));
        __syncthreads();
        if (__float_as_uint(bS) == sbits[rr]) atomicMin(&sidx[rr], bK);
        __syncthreads();
    }

    // stage 2: first-index tie-break among exact-score minima
    if (bestK != 0x7fffffff && __float_as_uint(bestS) == sbits[r])
        atomicMin(&sidx[r], bestK);
    __syncthreads();
    if (tid < 64) idxf[rowBase + tid] = (float)sidx[tid];
}

// -------- kernel 4: gather z_q + loss accumulation --------
__global__ __launch_bounds__(256) void vq_gather(
    const float* __restrict__ z, const float* __restrict__ emb,
    const float* __restrict__ idxf, float* __restrict__ zq,
    float* __restrict__ loss, float scale) {
    const int tid = threadIdx.x;
    const int lane = tid & 63, w = tid >> 6;
    const int rowBase = blockIdx.x * 64;
    float lsum = 0.f;
    for (int t = 0; t < 16; ++t) {
        int gr = rowBase + w * 16 + t;
        int k = (int)idxf[gr];
        k = (k < 0) ? 0 : ((k > 8191) ? 8191 : k);   // defensive clamp
        float4 e  = ((const float4*)emb)[(size_t)k * 64 + lane];
        float4 zv = ((const float4*)z)[(size_t)gr * 64 + lane];
        ((float4*)zq)[(size_t)gr * 64 + lane] = e;
        float dx = e.x - zv.x, dy = e.y - zv.y, dz = e.z - zv.z, dw = e.w - zv.w;
        lsum = fmaf(dx, dx, lsum); lsum = fmaf(dy, dy, lsum);
        lsum = fmaf(dz, dz, lsum); lsum = fmaf(dw, dw, lsum);
    }
    #pragma unroll
    for (int off = 32; off; off >>= 1) lsum += __shfl_down(lsum, off);
    __shared__ float ps[4];
    if (lane == 0) ps[w] = lsum;
    __syncthreads();
    if (tid == 0) atomicAdd(loss, (ps[0] + ps[1] + ps[2] + ps[3]) * scale);
}

extern "C" void kernel_launch(void* const* d_in, const int* in_sizes, int n_in,
                              void* d_out, int out_size, void* d_ws, size_t ws_size,
                              hipStream_t stream) {
    const float* z   = (const float*)d_in[0];
    const float* emb = (const float*)d_in[1];
    const int N = in_sizes[0] / D;   // 16384
    const int K = in_sizes[1] / D;   // 8192

    float* out  = (float*)d_out;
    float* zq   = out;
    const size_t Z = (size_t)N * D;  // 4,194,304 floats (16 MB region)
    float* loss = out + Z;
    float* idxf = loss + 1;

    // scratch in the zq region (overwritten by gather at the end):
    // ebf 4MB | znorm 64KB | enorm 32KB | cntG 64KB | candC 6.03MB | candS 6.03MB
    char* base = (char*)zq;
    unsigned short* ebf = (unsigned short*)base;
    float* znorm   = (float*)(base + (size_t)K * D * 2);
    float* enorm   = znorm + N;
    int* cntG      = (int*)(enorm + K);
    int* candC     = cntG + N;
    float* candS   = (float*)(candC + (size_t)N * CAPG);

    vq_ebfrag <<<K / 64, 512, 0, stream>>>(emb, ebf);
    vq_rownorm<<<(N + 255) / 256, 256, 0, stream>>>(z, znorm, N, loss, cntG);
    vq_rownorm<<<(K + 255) / 256, 256, 0, stream>>>(emb, enorm, K, nullptr, nullptr);
    vq_filter <<<(N / BM) * 4, 512, 0, stream>>>(z, ebf, enorm, cntG, candC, candS);
    vq_rescore<<<N / 64, 256, 0, stream>>>(z, emb, znorm, enorm, cntG, candC, candS, idxf, K);
    vq_gather <<<N / 64, 256, 0, stream>>>(z, emb, idxf, zq, loss,
                                           1.25f / ((float)N * (float)D));
}

// Round 22
// 203.525 us; speedup vs baseline: 1.1690x; 1.1690x over previous
//
#include <hip/hip_runtime.h>
#include <hip/hip_bf16.h>

#define D 256
#define BM 32
#define CAPG 92
#define MARGIN 2.5e-4f

typedef short bf16x8 __attribute__((ext_vector_type(8)));
typedef float f32x4 __attribute__((ext_vector_type(4)));

__device__ inline unsigned short f2bf(float f) {
    __hip_bfloat16 h = __float2bfloat16(f);
    return *reinterpret_cast<unsigned short*>(&h);
}
// order-preserving float -> uint (works for negatives; lower float = lower uint)
__device__ inline unsigned f2ord(float f) {
    unsigned u = __float_as_uint(f);
    return (u & 0x80000000u) ? ~u : (u | 0x80000000u);
}
__device__ inline float ord2f(unsigned u) {
    unsigned b = (u & 0x80000000u) ? (u ^ 0x80000000u) : ~u;
    return __uint_as_float(b);
}

// -------- kernel 0: fp32 emb -> bf16 in MFMA-fragment order (R9-verified) ----
__global__ __launch_bounds__(512) void vq_ebfrag(const float* __restrict__ emb,
                                                 unsigned short* __restrict__ ebf) {
    const int cb = blockIdx.x;          // 0..127
    const int tid = threadIdx.x;
    const int kc = tid >> 6;            // wave index == kc 0..7
    const int l = tid & 63;
    const int q = l >> 4, lm = l & 15;
    const float4* emb4 = (const float4*)emb;
    #pragma unroll
    for (int fc = 0; fc < 4; ++fc) {
        const int code = cb * 64 + fc * 16 + lm;
        float4 a = emb4[(size_t)code * 64 + kc * 8 + q * 2];
        float4 b = emb4[(size_t)code * 64 + kc * 8 + q * 2 + 1];
        ushort4 o0, o1;
        o0.x = f2bf(a.x); o0.y = f2bf(a.y); o0.z = f2bf(a.z); o0.w = f2bf(a.w);
        o1.x = f2bf(b.x); o1.y = f2bf(b.y); o1.z = f2bf(b.z); o1.w = f2bf(b.w);
        unsigned short* dst = ebf + (((size_t)(cb * 8 + kc) * 4 + fc) << 9) + l * 8;
        *(ushort4*)dst = o0;
        *(ushort4*)(dst + 4) = o1;
    }
}

// -------- kernel 1: fused sequential row sum-of-squares for z AND emb ---------
// r < N: znorm[r] from z; r >= N: enorm[r-N] from emb. Strict XLA chain kept.
__global__ __launch_bounds__(256) void vq_rownorm2(const float* __restrict__ z,
                                                   const float* __restrict__ emb,
                                                   float* __restrict__ znorm,
                                                   float* __restrict__ enorm,
                                                   int N, int K,
                                                   float* loss_zero, int* cntG) {
#pragma clang fp contract(off)
    int r = blockIdx.x * blockDim.x + threadIdx.x;
    if (r == 0) loss_zero[0] = 0.f;
    if (r >= N + K) return;
    const float* src = (r < N) ? (z + ((size_t)r << 8)) : (emb + ((size_t)(r - N) << 8));
    if (r < N) cntG[r] = 0;
    const float4* p4 = (const float4*)src;
    float s = 0.f;
    for (int i = 0; i < 64; ++i) {       // strict sequential mul+add, ascending d
        float4 v = p4[i];
        s = s + v.x * v.x;
        s = s + v.y * v.y;
        s = s + v.z * v.z;
        s = s + v.w * v.w;
    }
    if (r < N) znorm[r] = s; else enorm[r - N] = s;
}

// -------- kernel 2: half-split single-pass MFMA filter (R19 + setprio) --------
// block b: rows [(b&511)*32, +32), code half b>>9 (4096 codes, 8 tiles of 512)
__global__ __launch_bounds__(512, 4) void vq_filter(
    const float* __restrict__ z, const unsigned short* __restrict__ ebf,
    const float* __restrict__ enorm,
    int* __restrict__ cntG, int* __restrict__ candC, float* __restrict__ candS) {
    __shared__ unsigned short zsh[BM][264];   // 16,896 B
    __shared__ unsigned rowmin[BM];           // ORDERED-uint running min

    const int tid = threadIdx.x;
    const int w = tid >> 6;        // wave 0..7 (64-code column)
    const int l = tid & 63;
    const int q = l >> 4;          // 0..3
    const int lm = l & 15;
    const int b = blockIdx.x;
    const int rowBase = (b & 511) * BM;
    const int half = b >> 9;       // 0..1

    if (tid < BM) rowmin[tid] = 0xffffffffu;   // ordered +inf

    // stage z tile: load f32, convert to bf16 inline
    #pragma unroll
    for (int rc = 0; rc < 4; ++rc) {
        int i4 = tid + rc * 512;                  // 2048 float4s
        int row = i4 >> 6, c4 = i4 & 63;
        float4 v = ((const float4*)(z + ((size_t)(rowBase + row) << 8)))[c4];
        ushort4 o;
        o.x = f2bf(v.x); o.y = f2bf(v.y); o.z = f2bf(v.z); o.w = f2bf(v.w);
        *(ushort4*)&zsh[row][c4 * 4] = o;
    }
    __syncthreads();

    for (int t = 0; t < 8; ++t) {
        const int cb = half * 64 + t * 8 + w;        // wave's 64-code block
        const int codeBase = cb * 64;
        const unsigned short* fb = ebf + ((size_t)cb << 14);
        float ne[4];
        #pragma unroll
        for (int fc = 0; fc < 4; ++fc) ne[fc] = enorm[codeBase + fc * 16 + lm];

        f32x4 acc[2][4];
        #pragma unroll
        for (int a = 0; a < 2; ++a)
            #pragma unroll
            for (int c = 0; c < 4; ++c) acc[a][c] = (f32x4)0.f;

        #pragma unroll
        for (int kc = 0; kc < 8; ++kc) {
            bf16x8 af[2], bfr[4];
            af[0] = *(const bf16x8*)&zsh[lm][kc * 32 + q * 8];
            af[1] = *(const bf16x8*)&zsh[16 + lm][kc * 32 + q * 8];
            #pragma unroll
            for (int fc = 0; fc < 4; ++fc)   // contiguous 1 KB per wave-load
                bfr[fc] = *(const bf16x8*)(fb + kc * 2048 + fc * 512 + l * 8);
            __builtin_amdgcn_s_setprio(1);   // waves are phase-diverse (no barriers)
            #pragma unroll
            for (int fr = 0; fr < 2; ++fr)
                #pragma unroll
                for (int fc = 0; fc < 4; ++fc)
                    acc[fr][fc] = __builtin_amdgcn_mfma_f32_16x16x32_bf16(af[fr], bfr[fc], acc[fr][fc], 0, 0, 0);
            __builtin_amdgcn_s_setprio(0);
        }

        // ---- epilogue: s' = ne - 2g (NEGATIVE possible -> ordered atomics) ----
        f32x4 m4[2];
        #pragma unroll
        for (int fr = 0; fr < 2; ++fr) {
            #pragma unroll
            for (int e = 0; e < 4; ++e) {
                float m = 3.4e38f;
                #pragma unroll
                for (int fc = 0; fc < 4; ++fc) {
                    float s = ne[fc] - 2.0f * acc[fr][fc][e];
                    m = fminf(m, s);
                }
                m4[fr][e] = m;
                #pragma unroll
                for (int off = 1; off < 16; off <<= 1)
                    m = fminf(m, __shfl_xor(m, off));
                if (lm == 0)
                    atomicMin(&rowmin[fr * 16 + q * 4 + e], f2ord(m));
            }
        }
        // collect vs running threshold (ordered decode)
        #pragma unroll
        for (int fr = 0; fr < 2; ++fr) {
            uint4 u = *(const uint4*)&rowmin[fr * 16 + q * 4];
            f32x4 thr = {ord2f(u.x) + MARGIN, ord2f(u.y) + MARGIN,
                         ord2f(u.z) + MARGIN, ord2f(u.w) + MARGIN};
            #pragma unroll
            for (int e = 0; e < 4; ++e) {
                if (m4[fr][e] >= thr[e]) continue;   // fast skip
                int row = rowBase + fr * 16 + q * 4 + e;
                #pragma unroll
                for (int fc = 0; fc < 4; ++fc) {
                    float s = ne[fc] - 2.0f * acc[fr][fc][e];
                    if (s < thr[e]) {
                        int slot = atomicAdd(&cntG[row], 1);
                        if (slot < CAPG) {
                            candC[(size_t)row * CAPG + slot] = codeBase + fc * 16 + lm;
                            candS[(size_t)row * CAPG + slot] = s;
                        }
                    }
                }
            }
        }
    }
}

// -------- kernel 3: pruned exact rescore (bit-exact R2 semantics) --------
__global__ __launch_bounds__(256) void vq_rescore(
    const float* __restrict__ z, const float* __restrict__ emb,
    const float* __restrict__ znorm, const float* __restrict__ enorm,
    const int* __restrict__ cntG, const int* __restrict__ candC,
    const float* __restrict__ candS, float* __restrict__ idxf, int K) {
#pragma clang fp contract(off)
    __shared__ unsigned sapx[64];   // ordered min approx score
    __shared__ unsigned sbits[64];  // exact score bits (always >= 0)
    __shared__ int sidx[64];
    __shared__ int ovList[64];
    __shared__ int ovCnt;

    const int tid = threadIdx.x;
    const int rowBase = blockIdx.x * 64;
    if (tid < 64) { sapx[tid] = 0xffffffffu; sbits[tid] = 0xffffffffu; sidx[tid] = 0x7fffffff; }
    if (tid == 0) ovCnt = 0;
    __syncthreads();

    const int r = tid & 63;        // one row per lane
    const int c0 = tid >> 6;       // 4 workers per row
    const int grow = rowBase + r;
    const int n = min(cntG[grow], CAPG);

    // phase 1: min approx score over stored candidates (ordered atomics)
    {
        float amin = 3.4e38f;
        for (int c = c0; c < n; c += 4)
            amin = fminf(amin, candS[(size_t)grow * CAPG + c]);
        atomicMin(&sapx[r], f2ord(amin));
    }
    if (tid < 64 && cntG[rowBase + tid] > CAPG) {      // overflow rows -> exact scan
        int o = atomicAdd(&ovCnt, 1);
        ovList[o] = tid;                               // total safety
    }
    __syncthreads();

    // phase 2: exact rescore only candidates within MARGIN of min approx
    const float Anz = znorm[grow];
    const float4* zp4 = (const float4*)(z + ((size_t)grow << 8));
    const float athr = ord2f(sapx[r]) + MARGIN;

    float bestS = 3.4e38f; int bestK = 0x7fffffff;
    for (int c = c0; c < n; c += 4) {
        if (candS[(size_t)grow * CAPG + c] > athr) continue;   // pruned: 8B not 1KB
        int k = candC[(size_t)grow * CAPG + c];
        const float4* ep4 = (const float4*)(emb + ((size_t)k << 8));
        float s = 0.f;
        #pragma unroll 8
        for (int d4 = 0; d4 < 64; ++d4) {
            float4 a = zp4[d4], b = ep4[d4];
            s = s + a.x * b.x;   // strict mul-then-add, ascending d
            s = s + a.y * b.y;
            s = s + a.z * b.z;
            s = s + a.w * b.w;
        }
        float sc = (Anz + enorm[k]) - 2.0f * s;
        if (sc < bestS || (sc == bestS && k < bestK)) { bestS = sc; bestK = k; }
    }
    if (bestK != 0x7fffffff) atomicMin(&sbits[r], __float_as_uint(bestS));
    __syncthreads();

    // cooperative fallback: full exact scan for every overflow row
    const int nov = ovCnt;
    for (int o = 0; o < nov; ++o) {
        const int rr = ovList[o];
        const float Az = znorm[rowBase + rr];
        const float4* zr4 = (const float4*)(z + ((size_t)(rowBase + rr) << 8));
        float bS = 3.4e38f; int bK = 0x7fffffff;
        for (int k = tid; k < K; k += 256) {
            const float4* ep4 = (const float4*)(emb + ((size_t)k << 8));
            float s = 0.f;
            #pragma unroll 8
            for (int d4 = 0; d4 < 64; ++d4) {
                float4 a = zr4[d4], b = ep4[d4];
                s = s + a.x * b.x; s = s + a.y * b.y;
                s = s + a.z * b.z; s = s + a.w * b.w;
            }
            float sc = (Az + enorm[k]) - 2.0f * s;
            if (sc < bS || (sc == bS && k < bK)) { bS = sc; bK = k; }
        }
        atomicMin(&sbits[rr], __float_as_uint(bS));
        __syncthreads();
        if (__float_as_uint(bS) == sbits[rr]) atomicMin(&sidx[rr], bK);
        __syncthreads();
    }

    // stage 2: first-index tie-break among exact-score minima
    if (bestK != 0x7fffffff && __float_as_uint(bestS) == sbits[r])
        atomicMin(&sidx[r], bestK);
    __syncthreads();
    if (tid < 64) idxf[rowBase + tid] = (float)sidx[tid];
}

// -------- kernel 4: gather z_q + loss accumulation --------
__global__ __launch_bounds__(256) void vq_gather(
    const float* __restrict__ z, const float* __restrict__ emb,
    const float* __restrict__ idxf, float* __restrict__ zq,
    float* __restrict__ loss, float scale) {
    const int tid = threadIdx.x;
    const int lane = tid & 63, w = tid >> 6;
    const int rowBase = blockIdx.x * 64;
    float lsum = 0.f;
    for (int t = 0; t < 16; ++t) {
        int gr = rowBase + w * 16 + t;
        int k = (int)idxf[gr];
        k = (k < 0) ? 0 : ((k > 8191) ? 8191 : k);   // defensive clamp
        float4 e  = ((const float4*)emb)[(size_t)k * 64 + lane];
        float4 zv = ((const float4*)z)[(size_t)gr * 64 + lane];
        ((float4*)zq)[(size_t)gr * 64 + lane] = e;
        float dx = e.x - zv.x, dy = e.y - zv.y, dz = e.z - zv.z, dw = e.w - zv.w;
        lsum = fmaf(dx, dx, lsum); lsum = fmaf(dy, dy, lsum);
        lsum = fmaf(dz, dz, lsum); lsum = fmaf(dw, dw, lsum);
    }
    #pragma unroll
    for (int off = 32; off; off >>= 1) lsum += __shfl_down(lsum, off);
    __shared__ float ps[4];
    if (lane == 0) ps[w] = lsum;
    __syncthreads();
    if (tid == 0) atomicAdd(loss, (ps[0] + ps[1] + ps[2] + ps[3]) * scale);
}

extern "C" void kernel_launch(void* const* d_in, const int* in_sizes, int n_in,
                              void* d_out, int out_size, void* d_ws, size_t ws_size,
                              hipStream_t stream) {
    const float* z   = (const float*)d_in[0];
    const float* emb = (const float*)d_in[1];
    const int N = in_sizes[0] / D;   // 16384
    const int K = in_sizes[1] / D;   // 8192

    float* out  = (float*)d_out;
    float* zq   = out;
    const size_t Z = (size_t)N * D;  // 4,194,304 floats (16 MB region)
    float* loss = out + Z;
    float* idxf = loss + 1;

    // scratch in the zq region (overwritten by gather at the end):
    // ebf 4MB | znorm 64KB | enorm 32KB | cntG 64KB | candC 6.03MB | candS 6.03MB
    char* base = (char*)zq;
    unsigned short* ebf = (unsigned short*)base;
    float* znorm   = (float*)(base + (size_t)K * D * 2);
    float* enorm   = znorm + N;
    int* cntG      = (int*)(enorm + K);
    int* candC     = cntG + N;
    float* candS   = (float*)(candC + (size_t)N * CAPG);

    vq_ebfrag  <<<K / 64, 512, 0, stream>>>(emb, ebf);
    vq_rownorm2<<<(N + K + 255) / 256, 256, 0, stream>>>(z, emb, znorm, enorm, N, K, loss, cntG);
    vq_filter  <<<(N / BM) * 2, 512, 0, stream>>>(z, ebf, enorm, cntG, candC, candS);
    vq_rescore <<<N / 64, 256, 0, stream>>>(z, emb, znorm, enorm, cntG, candC, candS, idxf, K);
    vq_gather  <<<N / 64, 256, 0, stream>>>(z, emb, idxf, zq, loss,
                                            1.25f / ((float)N * (float)D));
}